// Round 14
// baseline (142.733 us; speedup 1.0000x reference)
//
#include <hip/hip_runtime.h>
#include <hip/hip_bf16.h>

// Local-window attention, B=32 S=1024(16x64) H=8 D=384/8=48, window 7x11.
// R14: (a) K1 q/k epilogue through LDS (stride-136 [row][col] tile, 8x16B
//      coalesced stores/thread instead of 64 2B-scatters); (b) K1 LDS cut to
//      34KB (2-buffer R7 loop, loop-perf-equivalent per R7/R9/R10) -> 4
//      blocks/CU (was 2); (c) attn PV band-skip: qt=0 skips c=1, qt=3 skips
//      c=0 (bit-identical, -6 of 24 PV MFMA). Everything else = R13 (passing).

typedef __attribute__((ext_vector_type(8))) unsigned short ushort8;
typedef __attribute__((ext_vector_type(4))) unsigned short ushort4v;
typedef __attribute__((ext_vector_type(8))) short short8v;
typedef __attribute__((ext_vector_type(4))) float floatx4;

__device__ __forceinline__ float bf2f(unsigned short u) {
  union { unsigned int i; float f; } x;
  x.i = ((unsigned int)u) << 16;
  return x.f;
}

__device__ __forceinline__ unsigned short f2bu(float f) {
  union { float f; unsigned int i; } x;
  x.f = f;
  unsigned int lsb = (x.i >> 16) & 1u;
  x.i += 0x7FFFu + lsb;  // RNE
  return (unsigned short)(x.i >> 16);
}

__device__ __forceinline__ void gload_lds16(const void* g, void* l) {
  __builtin_amdgcn_global_load_lds(
      (const __attribute__((address_space(1))) unsigned int*)g,
      (__attribute__((address_space(3))) unsigned int*)l, 16, 0, 0);
}

// ---------------- K0a: f32 -> bf16 ----------------
__global__ __launch_bounds__(256) void cvt_f32_bf16(
    const float4* __restrict__ in, ushort4v* __restrict__ out, int n4) {
  const int i = blockIdx.x * 256 + threadIdx.x;
  if (i < n4) {
    const float4 v = in[i];
    ushort4v o;
    o[0] = f2bu(v.x); o[1] = f2bu(v.y); o[2] = f2bu(v.z); o[3] = f2bu(v.w);
    out[i] = o;
  }
}

// ---------------- K0b/c: transpose f32 [R][C] -> bf16 [C][R] ----------------
__global__ __launch_bounds__(256) void transpose_cvt(
    const float* __restrict__ in, unsigned short* __restrict__ out, int R, int C) {
  __shared__ float t[32][33];
  const int c0 = blockIdx.x * 32, r0 = blockIdx.y * 32;
  const int tx = threadIdx.x, ty = threadIdx.y;
  #pragma unroll
  for (int rr = ty; rr < 32; rr += 8) t[rr][tx] = in[(size_t)(r0 + rr) * C + c0 + tx];
  __syncthreads();
  #pragma unroll
  for (int rr = ty; rr < 32; rr += 8)
    out[(size_t)(c0 + rr) * R + r0 + tx] = f2bu(t[tx][rr]);
}

// ---------------- MFMA GEMM, 2-buffer pipelined K-loop, LDS epilogues --------
// smem = max(2x(A+B) staging = 16384 shorts, transpose tile 128*136 = 17408)
// = 17408 shorts (34KB) -> 4 blocks/CU.
template <int MODE>
__global__ __launch_bounds__(256) void gemm_mfma(
    const unsigned short* __restrict__ A,   // [M][384] bf16
    const unsigned short* __restrict__ Bt,  // [N][384] bf16 (= B^T)
    const float* __restrict__ bias, float* __restrict__ outf,
    unsigned short* __restrict__ qws, unsigned short* __restrict__ kws,
    unsigned short* __restrict__ vtws)
{
  __shared__ unsigned short smem[17408];  // 34KB
  const int tid = threadIdx.x;
  const int lane = tid & 63, w = tid >> 6;
  const int wm = w & 1, wn = w >> 1;

  // chunked XCD swizzle
  const int nbx = gridDim.x;
  const int nwg = nbx * gridDim.y;
  const int bid = blockIdx.y * nbx + blockIdx.x;
  const int swz = (bid & 7) * (nwg >> 3) + (bid >> 3);
  const int n0 = (swz % nbx) * 128;
  const int m0 = (swz / nbx) * 128;

  floatx4 acc[4][4];
  #pragma unroll
  for (int mi = 0; mi < 4; ++mi)
    #pragma unroll
    for (int ni = 0; ni < 4; ++ni)
      acc[mi][ni] = (floatx4){0.f, 0.f, 0.f, 0.f};

  const int srow = w * 16 + (lane >> 2);
  const int kslot16 = (lane & 3) * 16;

  auto ASB = [&](int buf) -> unsigned short* { return smem + buf * 4096; };
  auto BSB = [&](int buf) -> unsigned short* { return smem + 8192 + buf * 4096; };

  auto STAGE = [&](int buf, int k0) {
    #pragma unroll
    for (int c = 0; c < 2; ++c) {
      const int r = c * 64 + srow;
      const int kb = kslot16 ^ ((r & 3) << 4);
      gload_lds16((const char*)A + (size_t)(m0 + r) * 768 + k0 * 2 + kb,
                  (char*)ASB(buf) + c * 4096 + w * 1024);
      gload_lds16((const char*)Bt + (size_t)(n0 + r) * 768 + k0 * 2 + kb,
                  (char*)BSB(buf) + c * 4096 + w * 1024);
    }
  };

  auto COMPUTE = [&](int buf) {
    short8v a[4], b[4];
    const int kgb = (lane >> 4) * 16;
    #pragma unroll
    for (int mi = 0; mi < 4; ++mi) {
      const int r = wm * 64 + mi * 16 + (lane & 15);
      a[mi] = *reinterpret_cast<const short8v*>(
          (const char*)ASB(buf) + r * 64 + (kgb ^ ((r & 3) << 4)));
    }
    #pragma unroll
    for (int ni = 0; ni < 4; ++ni) {
      const int r = wn * 64 + ni * 16 + (lane & 15);
      b[ni] = *reinterpret_cast<const short8v*>(
          (const char*)BSB(buf) + r * 64 + (kgb ^ ((r & 3) << 4)));
    }
    #pragma unroll
    for (int mi = 0; mi < 4; ++mi)
      #pragma unroll
      for (int ni = 0; ni < 4; ++ni)
        acc[mi][ni] = __builtin_amdgcn_mfma_f32_16x16x32_bf16(
            a[mi], b[ni], acc[mi][ni], 0, 0, 0);
  };

  STAGE(0, 0);

  for (int t = 0; t < 12; ++t) {
    const int cur = t & 1;
    if (t < 11) {
      STAGE(cur ^ 1, (t + 1) * 32);                    // prefetch next tile
      asm volatile("s_waitcnt vmcnt(4)" ::: "memory"); // cur's loads done
    } else {
      asm volatile("s_waitcnt vmcnt(0)" ::: "memory");
    }
    __builtin_amdgcn_s_barrier();
    __builtin_amdgcn_s_setprio(1);
    COMPUTE(cur);
    __builtin_amdgcn_s_setprio(0);
    asm volatile("s_waitcnt lgkmcnt(0)" ::: "memory");
    __builtin_amdgcn_s_barrier();
  }

  const int col_l = lane & 15;
  const int row_l = (lane >> 4) * 4;

  if (MODE == 0) {
    const float QSCALE = 0.14433756729740643f;  // 1/sqrt(48)
    const int which = n0 / 384;  // uniform per block (384 | 128*{0,3,6})
    if (which < 2) {
      // q/k: C-tile -> LDS [row][col] (stride 136), then 8 x 16B coalesced
      // stores per thread. Chunk (8 shorts) never straddles an h boundary
      // (8 | 48, n0%384 multiple of 8).
      unsigned short* T = smem;  // 128*136 = 17408 shorts
      const float scale = (which == 0) ? QSCALE : 1.f;
      #pragma unroll
      for (int ni = 0; ni < 4; ++ni) {
        const int col = wn * 64 + ni * 16 + col_l;
        #pragma unroll
        for (int mi = 0; mi < 4; ++mi) {
          const int rowb = wm * 64 + mi * 16 + row_l;
          #pragma unroll
          for (int reg = 0; reg < 4; ++reg)
            T[(rowb + reg) * 136 + col] = f2bu(acc[mi][ni][reg] * scale);
        }
      }
      __syncthreads();
      unsigned short* dstb = (which == 0) ? qws : kws;
      const int row = tid >> 1, half = tid & 1;
      const int s = (m0 & 1023) + row;
      const int bb = m0 >> 10;
      const int base_rem = n0 - which * 384;  // 0,128,256
      #pragma unroll
      for (int j = 0; j < 8; ++j) {
        const int c = half * 64 + j * 8;
        const int rem = base_rem + c;
        const int h = rem / 48, d = rem - h * 48;
        unsigned short* dst =
            dstb + (((size_t)(bb * 8 + h)) * 1024 + s) * 48 + d;
        *reinterpret_cast<ushort8*>(dst) =
            *reinterpret_cast<const ushort8*>(&T[row * 136 + c]);
      }
    } else {
      // V: transpose C-tile through LDS, coalesced vt writes (R11-verified)
      unsigned short* T = smem;
      #pragma unroll
      for (int ni = 0; ni < 4; ++ni) {
        const int col = wn * 64 + ni * 16 + col_l;
        #pragma unroll
        for (int mi = 0; mi < 4; ++mi) {
          const int rowb = wm * 64 + mi * 16 + row_l;
          #pragma unroll
          for (int reg = 0; reg < 4; ++reg)
            T[col * 136 + rowb + reg] = f2bu(acc[mi][ni][reg]);
        }
      }
      __syncthreads();
      const int col = tid >> 1, half = tid & 1;
      const int cg = n0 + col;
      const int rem = cg - 768;
      const int h = rem / 48, d = rem - h * 48;
      const int bb = m0 >> 10;
      const int s0 = (m0 & 1023) + half * 64;
      unsigned short* dst =
          vtws + (((size_t)(bb * 8 + h)) * 48 + d) * 1024 + s0;
      const unsigned short* src = T + col * 136 + half * 64;
      #pragma unroll
      for (int j = 0; j < 8; ++j)
        *reinterpret_cast<ushort8*>(dst + j * 8) =
            *reinterpret_cast<const ushort8*>(src + j * 8);
    }
  } else {
    #pragma unroll
    for (int ni = 0; ni < 4; ++ni) {
      const int cg = n0 + wn * 64 + ni * 16 + col_l;
      const float bv = bias[cg];
      #pragma unroll
      for (int mi = 0; mi < 4; ++mi) {
        #pragma unroll
        for (int reg = 0; reg < 4; ++reg) {
          const int r = m0 + wm * 64 + mi * 16 + row_l + reg;
          outf[(size_t)r * 384 + cg] = acc[mi][ni][reg] + bv;
        }
      }
    }
  }
}

// ---------------- K2: MFMA local attention (R13 + PV band-skip) ----------
__global__ __launch_bounds__(256) void attn_mfma(
    const unsigned short* __restrict__ qws,  // [bh][1024][48]
    const unsigned short* __restrict__ kws,  // [bh][1024][48]
    const unsigned short* __restrict__ vt,   // [bh][48][1024]
    unsigned short* __restrict__ attn_out)   // [b*1024][384] bf16
{
  __shared__ unsigned short plds_all[4 * 64 * 72];

  const int tid = threadIdx.x;
  const int w = tid >> 6;
  const int lane = tid & 63;
  const int blk = blockIdx.x;
  const int sw = ((blk & 7) << 7) | (blk >> 3);  // 1024 % 8 == 0
  const int task = sw * 4 + w;
  const int i  = task & 15;
  const int bh = task >> 4;
  const int ql = lane & 15;
  const int g  = lane >> 4;

  unsigned short* plds = plds_all + w * 4608;  // 64*72 per wave

  // zero plds once: band-external tiles stay 0 forever -> PV adds exact zeros
  {
    const uint4 zz = make_uint4(0, 0, 0, 0);
    #pragma unroll
    for (int z = 0; z < 9; ++z)
      reinterpret_cast<uint4*>(plds)[lane + z * 64] = zz;
  }

  const unsigned short* qbase = qws + (size_t)bh * 1024 * 48;
  const unsigned short* kbase = kws + (size_t)bh * 1024 * 48;
  const unsigned short* vbase = vt  + (size_t)bh * 48 * 1024;

  const short8v zfrag = (short8v){0, 0, 0, 0, 0, 0, 0, 0};

  short8v qf[4][2];
  #pragma unroll
  for (int qt = 0; qt < 4; ++qt) {
    const unsigned short* qrow = qbase + (size_t)(i * 64 + qt * 16 + ql) * 48;
    qf[qt][0] = *reinterpret_cast<const short8v*>(qrow + 8 * g);
    qf[qt][1] = (g < 2) ? *reinterpret_cast<const short8v*>(qrow + 32 + 8 * g)
                        : zfrag;
  }

  floatx4 ot[3][4];
  #pragma unroll
  for (int dt = 0; dt < 3; ++dt)
    #pragma unroll
    for (int qt = 0; qt < 4; ++qt)
      ot[dt][qt] = (floatx4){0.f, 0.f, 0.f, 0.f};
  float mreg[4] = {-INFINITY, -INFINITY, -INFINITY, -INFINITY};
  float lreg[4] = {0.f, 0.f, 0.f, 0.f};

  const int ki0 = (i - 3 < 0) ? 0 : i - 3;
  const int ki1 = (i + 3 > 15) ? 15 : i + 3;

  for (int ki = ki0; ki <= ki1; ++ki) {
    short8v kf[4][2];
    #pragma unroll
    for (int kt = 0; kt < 4; ++kt) {
      const unsigned short* krow = kbase + (size_t)(ki * 64 + kt * 16 + ql) * 48;
      kf[kt][0] = *reinterpret_cast<const short8v*>(krow + 8 * g);
      kf[kt][1] = (g < 2) ? *reinterpret_cast<const short8v*>(krow + 32 + 8 * g)
                          : zfrag;
    }
    short8v vf[3][2];
    #pragma unroll
    for (int dt = 0; dt < 3; ++dt)
      #pragma unroll
      for (int c = 0; c < 2; ++c)
        vf[dt][c] = *reinterpret_cast<const short8v*>(
            vbase + (size_t)(16 * dt + ql) * 1024 + ki * 64 + 32 * c + 8 * g);

    #pragma unroll
    for (int qt = 0; qt < 4; ++qt) {
      const int kts = (qt == 0) ? 0 : qt - 1;
      const int kte = (qt == 3) ? 3 : qt + 1;
      floatx4 s[4];
      #pragma unroll
      for (int kt = 0; kt < 4; ++kt) {
        if (kt < kts || kt > kte) continue;
        s[kt] = __builtin_amdgcn_mfma_f32_16x16x32_bf16(
            kf[kt][0], qf[qt][0], (floatx4){0.f, 0.f, 0.f, 0.f}, 0, 0, 0);
        s[kt] = __builtin_amdgcn_mfma_f32_16x16x32_bf16(
            kf[kt][1], qf[qt][1], s[kt], 0, 0, 0);
      }
      const int qcol = qt * 16 + ql;
      float pmax = -INFINITY;
      #pragma unroll
      for (int kt = 0; kt < 4; ++kt) {
        if (kt < kts || kt > kte) continue;
        #pragma unroll
        for (int r = 0; r < 4; ++r) {
          const int delta = kt * 16 + 4 * g + r - qcol;
          const bool ok = (delta <= 5) && (delta >= -5);
          s[kt][r] = ok ? s[kt][r] : -INFINITY;
          pmax = fmaxf(pmax, s[kt][r]);
        }
      }
      // defer-max (first ki: m=-inf -> always rescales/initializes)
      if (!__all(pmax - mreg[qt] <= 8.0f)) {
        float mt = fmaxf(pmax, __shfl_xor(pmax, 16, 64));
        mt = fmaxf(mt, __shfl_xor(mt, 32, 64));
        const float mnew = fmaxf(mreg[qt], mt);
        const float corr = __expf(mreg[qt] - mnew);
        lreg[qt] *= corr;
        #pragma unroll
        for (int dt = 0; dt < 3; ++dt) {
          ot[dt][qt][0] *= corr; ot[dt][qt][1] *= corr;
          ot[dt][qt][2] *= corr; ot[dt][qt][3] *= corr;
        }
        mreg[qt] = mnew;
      }
      float ps = 0.f;
      #pragma unroll
      for (int kt = 0; kt < 4; ++kt) {
        if (kt < kts || kt > kte) continue;
        #pragma unroll
        for (int r = 0; r < 4; ++r) {
          const float p = __expf(s[kt][r] - mreg[qt]);
          s[kt][r] = p;
          ps += p;
        }
      }
      ps += __shfl_xor(ps, 16, 64);
      ps += __shfl_xor(ps, 32, 64);
      lreg[qt] += ps;
      #pragma unroll
      for (int kt = 0; kt < 4; ++kt) {
        if (kt < kts || kt > kte) continue;
        uint2 pk;
        pk.x = (unsigned int)f2bu(s[kt][0]) | ((unsigned int)f2bu(s[kt][1]) << 16);
        pk.y = (unsigned int)f2bu(s[kt][2]) | ((unsigned int)f2bu(s[kt][3]) << 16);
        *reinterpret_cast<uint2*>(&plds[(qt * 16 + ql) * 72 + kt * 16 + 4 * g]) = pk;
      }
    }

    // PV band-skip: qt=0 band is k<32 (skip c=1); qt=3 band is k>=32 (skip c=0)
    __builtin_amdgcn_s_setprio(1);
    #pragma unroll
    for (int qt = 0; qt < 4; ++qt) {
      #pragma unroll
      for (int c = 0; c < 2; ++c) {
        if ((qt == 0 && c == 1) || (qt == 3 && c == 0)) continue;
        const short8v pf = *reinterpret_cast<const short8v*>(
            &plds[(qt * 16 + ql) * 72 + 32 * c + 8 * g]);
        #pragma unroll
        for (int dt = 0; dt < 3; ++dt)
          ot[dt][qt] = __builtin_amdgcn_mfma_f32_16x16x32_bf16(
              vf[dt][c], pf, ot[dt][qt], 0, 0, 0);
      }
    }
    __builtin_amdgcn_s_setprio(0);
  }

  // epilogue: normalize, store O^T -> attn_out[(b, i*64+q)][h*48 + d]
  const int b = bh >> 3, h = bh & 7;
  #pragma unroll
  for (int qt = 0; qt < 4; ++qt) {
    const float inv = 1.0f / lreg[qt];
    unsigned short* orow =
        attn_out + (size_t)(b * 1024 + i * 64 + qt * 16 + ql) * 384 + h * 48;
    #pragma unroll
    for (int dt = 0; dt < 3; ++dt) {
      const int d0 = 16 * dt + 4 * g;
      unsigned int w0 = (unsigned int)f2bu(ot[dt][qt][0] * inv) |
                        ((unsigned int)f2bu(ot[dt][qt][1] * inv) << 16);
      unsigned int w1 = (unsigned int)f2bu(ot[dt][qt][2] * inv) |
                        ((unsigned int)f2bu(ot[dt][qt][3] * inv) << 16);
      *reinterpret_cast<unsigned int*>(orow + d0)     = w0;
      *reinterpret_cast<unsigned int*>(orow + d0 + 2) = w1;
    }
  }
}

extern "C" void kernel_launch(void* const* d_in, const int* in_sizes, int n_in,
                              void* d_out, int out_size, void* d_ws, size_t ws_size,
                              hipStream_t stream) {
  const float* x      = (const float*)d_in[0];
  const float* w_qkv  = (const float*)d_in[1];
  const float* w_proj = (const float*)d_in[2];
  const float* b_proj = (const float*)d_in[3];
  // d_in[4] (mask) unused: window is analytic (|di|<=3, |dj|<=5)

  const size_t T = 25165824;  // 32768*384*2 bytes
  char* ws = (char*)d_ws;
  unsigned short* xb    = (unsigned short*)ws;            // aliased with attn_out
  unsigned short* qws   = (unsigned short*)(ws + T);
  unsigned short* kws   = (unsigned short*)(ws + 2 * T);
  unsigned short* vtws  = (unsigned short*)(ws + 3 * T);  // [bh][48][1024]
  unsigned short* wqkvT = (unsigned short*)(ws + 4 * T);
  unsigned short* wpT   = (unsigned short*)(ws + 4 * T + 884736);
  unsigned short* attn_out = xb;  // xb dead after K1
  float* out = (float*)d_out;

  // K0: conversions
  cvt_f32_bf16<<<12288, 256, 0, stream>>>((const float4*)x, (ushort4v*)xb, 3145728);
  transpose_cvt<<<dim3(36, 12), dim3(32, 8), 0, stream>>>(w_qkv, wqkvT, 384, 1152);
  transpose_cvt<<<dim3(12, 12), dim3(32, 8), 0, stream>>>(w_proj, wpT, 384, 384);

  // K1: qkv GEMM (M=32768, K=384, N=1152) -> q/k [bh][s][48], v^T [bh][48][s]
  gemm_mfma<0><<<dim3(9, 256), 256, 0, stream>>>(xb, wqkvT, nullptr, nullptr,
                                                 qws, kws, vtws);
  // K2: MFMA local attention -> attn_out bf16 [B*S, 384]
  attn_mfma<<<dim3(1024), 256, 0, stream>>>(qws, kws, vtws, attn_out);
  // K3: out = attn_out @ w_proj + bias (N=384), f32 out
  gemm_mfma<1><<<dim3(3, 256), 256, 0, stream>>>(attn_out, wpT, b_proj, out,
                                                 nullptr, nullptr, nullptr);
}

// Round 15
// 141.901 us; speedup vs baseline: 1.0059x; 1.0059x over previous
//
#include <hip/hip_runtime.h>
#include <hip/hip_bf16.h>

// Local-window attention, B=32 S=1024(16x64) H=8 D=384/8=48, window 7x11.
// R15: decouple R14's confound — keep R13's BK=64 4-buffer K-loop (best
//      measured: 54us) AND R14's q/k LDS-coalesced epilogue (R11's V fix
//      analog). T-tile aliases dead staging (64KB total, = R13 footprint).
//      attn keeps R14's PV band-skip. Everything else unchanged.

typedef __attribute__((ext_vector_type(8))) unsigned short ushort8;
typedef __attribute__((ext_vector_type(4))) unsigned short ushort4v;
typedef __attribute__((ext_vector_type(8))) short short8v;
typedef __attribute__((ext_vector_type(4))) float floatx4;

__device__ __forceinline__ float bf2f(unsigned short u) {
  union { unsigned int i; float f; } x;
  x.i = ((unsigned int)u) << 16;
  return x.f;
}

__device__ __forceinline__ unsigned short f2bu(float f) {
  union { float f; unsigned int i; } x;
  x.f = f;
  unsigned int lsb = (x.i >> 16) & 1u;
  x.i += 0x7FFFu + lsb;  // RNE
  return (unsigned short)(x.i >> 16);
}

__device__ __forceinline__ void gload_lds16(const void* g, void* l) {
  __builtin_amdgcn_global_load_lds(
      (const __attribute__((address_space(1))) unsigned int*)g,
      (__attribute__((address_space(3))) unsigned int*)l, 16, 0, 0);
}

// ---------------- K0a: f32 -> bf16 ----------------
__global__ __launch_bounds__(256) void cvt_f32_bf16(
    const float4* __restrict__ in, ushort4v* __restrict__ out, int n4) {
  const int i = blockIdx.x * 256 + threadIdx.x;
  if (i < n4) {
    const float4 v = in[i];
    ushort4v o;
    o[0] = f2bu(v.x); o[1] = f2bu(v.y); o[2] = f2bu(v.z); o[3] = f2bu(v.w);
    out[i] = o;
  }
}

// ---------------- K0b/c: transpose f32 [R][C] -> bf16 [C][R] ----------------
__global__ __launch_bounds__(256) void transpose_cvt(
    const float* __restrict__ in, unsigned short* __restrict__ out, int R, int C) {
  __shared__ float t[32][33];
  const int c0 = blockIdx.x * 32, r0 = blockIdx.y * 32;
  const int tx = threadIdx.x, ty = threadIdx.y;
  #pragma unroll
  for (int rr = ty; rr < 32; rr += 8) t[rr][tx] = in[(size_t)(r0 + rr) * C + c0 + tx];
  __syncthreads();
  #pragma unroll
  for (int rr = ty; rr < 32; rr += 8)
    out[(size_t)(c0 + rr) * R + r0 + tx] = f2bu(t[tx][rr]);
}

// ---------------- MFMA GEMM: BK=64 4-buffer loop + LDS epilogues ----------
// K-loop = R13 (best measured). Epilogues: q/k via [row][col] T-tile then
// 8x16B coalesced stores/thread; V via [col][row] T-tile (R11). T aliases
// staging (dead after loop): smem = 32768 shorts = 64KB.
template <int MODE>
__global__ __launch_bounds__(256) void gemm_mfma(
    const unsigned short* __restrict__ A,   // [M][384] bf16
    const unsigned short* __restrict__ Bt,  // [N][384] bf16 (= B^T)
    const float* __restrict__ bias, float* __restrict__ outf,
    unsigned short* __restrict__ qws, unsigned short* __restrict__ kws,
    unsigned short* __restrict__ vtws)
{
  __shared__ unsigned short smem[32768];  // 64KB
  const int tid = threadIdx.x;
  const int lane = tid & 63, w = tid >> 6;
  const int wm = w & 1, wn = w >> 1;

  // chunked XCD swizzle
  const int nbx = gridDim.x;
  const int nwg = nbx * gridDim.y;
  const int bid = blockIdx.y * nbx + blockIdx.x;
  const int swz = (bid & 7) * (nwg >> 3) + (bid >> 3);
  const int n0 = (swz % nbx) * 128;
  const int m0 = (swz / nbx) * 128;

  floatx4 acc[4][4];
  #pragma unroll
  for (int mi = 0; mi < 4; ++mi)
    #pragma unroll
    for (int ni = 0; ni < 4; ++ni)
      acc[mi][ni] = (floatx4){0.f, 0.f, 0.f, 0.f};

  const int srow = w * 16 + (lane >> 2);
  const int kslot16 = (lane & 3) * 16;

  auto ASB = [&](int buf) -> unsigned short* { return smem + buf * 4096; };
  auto BSB = [&](int buf) -> unsigned short* { return smem + 16384 + buf * 4096; };

  auto STAGE = [&](int buf, int k0) {
    #pragma unroll
    for (int c = 0; c < 2; ++c) {
      const int r = c * 64 + srow;
      const int kb = kslot16 ^ ((r & 3) << 4);
      gload_lds16((const char*)A + (size_t)(m0 + r) * 768 + k0 * 2 + kb,
                  (char*)ASB(buf) + c * 4096 + w * 1024);
      gload_lds16((const char*)Bt + (size_t)(n0 + r) * 768 + k0 * 2 + kb,
                  (char*)BSB(buf) + c * 4096 + w * 1024);
    }
  };

  auto COMPUTE = [&](int buf) {
    short8v a[4], b[4];
    const int kgb = (lane >> 4) * 16;
    #pragma unroll
    for (int mi = 0; mi < 4; ++mi) {
      const int r = wm * 64 + mi * 16 + (lane & 15);
      a[mi] = *reinterpret_cast<const short8v*>(
          (const char*)ASB(buf) + r * 64 + (kgb ^ ((r & 3) << 4)));
    }
    #pragma unroll
    for (int ni = 0; ni < 4; ++ni) {
      const int r = wn * 64 + ni * 16 + (lane & 15);
      b[ni] = *reinterpret_cast<const short8v*>(
          (const char*)BSB(buf) + r * 64 + (kgb ^ ((r & 3) << 4)));
    }
    #pragma unroll
    for (int mi = 0; mi < 4; ++mi)
      #pragma unroll
      for (int ni = 0; ni < 4; ++ni)
        acc[mi][ni] = __builtin_amdgcn_mfma_f32_16x16x32_bf16(
            a[mi], b[ni], acc[mi][ni], 0, 0, 0);
  };

  STAGE(0, 0);
  STAGE(1, 32);

  #pragma unroll
  for (int s = 0; s < 6; ++s) {
    const int rb = (s & 1) * 2;  // read bufs rb, rb+1 (tiles 2s, 2s+1)
    const int sb = rb ^ 2;       // stage bufs (tiles 2s+2, 2s+3)
    if (s < 5) {
      STAGE(sb, (2 * s + 2) * 32);
      STAGE(sb + 1, (2 * s + 3) * 32);
      asm volatile("s_waitcnt vmcnt(8)" ::: "memory");  // read-pair loads done
    } else {
      asm volatile("s_waitcnt vmcnt(0)" ::: "memory");
    }
    __builtin_amdgcn_s_barrier();
    __builtin_amdgcn_s_setprio(1);
    COMPUTE(rb);
    COMPUTE(rb + 1);
    __builtin_amdgcn_s_setprio(0);
    asm volatile("s_waitcnt lgkmcnt(0)" ::: "memory");
    __builtin_amdgcn_s_barrier();
  }

  const int col_l = lane & 15;
  const int row_l = (lane >> 4) * 4;

  if (MODE == 0) {
    const float QSCALE = 0.14433756729740643f;  // 1/sqrt(48)
    const int which = n0 / 384;  // uniform per block (384 | 128*{0,3,6})
    if (which < 2) {
      // q/k: C-tile -> LDS [row][col] (stride 136), then 8 x 16B coalesced
      // stores per thread. Chunk (8 shorts) never straddles an h boundary.
      unsigned short* T = smem;  // 128*136 = 17408 shorts, aliases staging
      const float scale = (which == 0) ? QSCALE : 1.f;
      #pragma unroll
      for (int ni = 0; ni < 4; ++ni) {
        const int col = wn * 64 + ni * 16 + col_l;
        #pragma unroll
        for (int mi = 0; mi < 4; ++mi) {
          const int rowb = wm * 64 + mi * 16 + row_l;
          #pragma unroll
          for (int reg = 0; reg < 4; ++reg)
            T[(rowb + reg) * 136 + col] = f2bu(acc[mi][ni][reg] * scale);
        }
      }
      __syncthreads();
      unsigned short* dstb = (which == 0) ? qws : kws;
      const int row = tid >> 1, half = tid & 1;
      const int s = (m0 & 1023) + row;
      const int bb = m0 >> 10;
      const int base_rem = n0 - which * 384;  // 0,128,256
      #pragma unroll
      for (int j = 0; j < 8; ++j) {
        const int c = half * 64 + j * 8;
        const int rem = base_rem + c;
        const int h = rem / 48, d = rem - h * 48;
        unsigned short* dst =
            dstb + (((size_t)(bb * 8 + h)) * 1024 + s) * 48 + d;
        *reinterpret_cast<ushort8*>(dst) =
            *reinterpret_cast<const ushort8*>(&T[row * 136 + c]);
      }
    } else {
      // V: transpose C-tile through LDS, coalesced vt writes (R11-verified)
      unsigned short* T = smem;
      #pragma unroll
      for (int ni = 0; ni < 4; ++ni) {
        const int col = wn * 64 + ni * 16 + col_l;
        #pragma unroll
        for (int mi = 0; mi < 4; ++mi) {
          const int rowb = wm * 64 + mi * 16 + row_l;
          #pragma unroll
          for (int reg = 0; reg < 4; ++reg)
            T[col * 136 + rowb + reg] = f2bu(acc[mi][ni][reg]);
        }
      }
      __syncthreads();
      const int col = tid >> 1, half = tid & 1;
      const int cg = n0 + col;
      const int rem = cg - 768;
      const int h = rem / 48, d = rem - h * 48;
      const int bb = m0 >> 10;
      const int s0 = (m0 & 1023) + half * 64;
      unsigned short* dst =
          vtws + (((size_t)(bb * 8 + h)) * 48 + d) * 1024 + s0;
      const unsigned short* src = T + col * 136 + half * 64;
      #pragma unroll
      for (int j = 0; j < 8; ++j)
        *reinterpret_cast<ushort8*>(dst + j * 8) =
            *reinterpret_cast<const ushort8*>(src + j * 8);
    }
  } else {
    #pragma unroll
    for (int ni = 0; ni < 4; ++ni) {
      const int cg = n0 + wn * 64 + ni * 16 + col_l;
      const float bv = bias[cg];
      #pragma unroll
      for (int mi = 0; mi < 4; ++mi) {
        #pragma unroll
        for (int reg = 0; reg < 4; ++reg) {
          const int r = m0 + wm * 64 + mi * 16 + row_l + reg;
          outf[(size_t)r * 384 + cg] = acc[mi][ni][reg] + bv;
        }
      }
    }
  }
}

// ---------------- K2: MFMA local attention (R14: band-skip + defer-max + PV skip) ----
__global__ __launch_bounds__(256) void attn_mfma(
    const unsigned short* __restrict__ qws,  // [bh][1024][48]
    const unsigned short* __restrict__ kws,  // [bh][1024][48]
    const unsigned short* __restrict__ vt,   // [bh][48][1024]
    unsigned short* __restrict__ attn_out)   // [b*1024][384] bf16
{
  __shared__ unsigned short plds_all[4 * 64 * 72];

  const int tid = threadIdx.x;
  const int w = tid >> 6;
  const int lane = tid & 63;
  const int blk = blockIdx.x;
  const int sw = ((blk & 7) << 7) | (blk >> 3);  // 1024 % 8 == 0
  const int task = sw * 4 + w;
  const int i  = task & 15;
  const int bh = task >> 4;
  const int ql = lane & 15;
  const int g  = lane >> 4;

  unsigned short* plds = plds_all + w * 4608;  // 64*72 per wave

  // zero plds once: band-external tiles stay 0 forever -> PV adds exact zeros
  {
    const uint4 zz = make_uint4(0, 0, 0, 0);
    #pragma unroll
    for (int z = 0; z < 9; ++z)
      reinterpret_cast<uint4*>(plds)[lane + z * 64] = zz;
  }

  const unsigned short* qbase = qws + (size_t)bh * 1024 * 48;
  const unsigned short* kbase = kws + (size_t)bh * 1024 * 48;
  const unsigned short* vbase = vt  + (size_t)bh * 48 * 1024;

  const short8v zfrag = (short8v){0, 0, 0, 0, 0, 0, 0, 0};

  short8v qf[4][2];
  #pragma unroll
  for (int qt = 0; qt < 4; ++qt) {
    const unsigned short* qrow = qbase + (size_t)(i * 64 + qt * 16 + ql) * 48;
    qf[qt][0] = *reinterpret_cast<const short8v*>(qrow + 8 * g);
    qf[qt][1] = (g < 2) ? *reinterpret_cast<const short8v*>(qrow + 32 + 8 * g)
                        : zfrag;
  }

  floatx4 ot[3][4];
  #pragma unroll
  for (int dt = 0; dt < 3; ++dt)
    #pragma unroll
    for (int qt = 0; qt < 4; ++qt)
      ot[dt][qt] = (floatx4){0.f, 0.f, 0.f, 0.f};
  float mreg[4] = {-INFINITY, -INFINITY, -INFINITY, -INFINITY};
  float lreg[4] = {0.f, 0.f, 0.f, 0.f};

  const int ki0 = (i - 3 < 0) ? 0 : i - 3;
  const int ki1 = (i + 3 > 15) ? 15 : i + 3;

  for (int ki = ki0; ki <= ki1; ++ki) {
    short8v kf[4][2];
    #pragma unroll
    for (int kt = 0; kt < 4; ++kt) {
      const unsigned short* krow = kbase + (size_t)(ki * 64 + kt * 16 + ql) * 48;
      kf[kt][0] = *reinterpret_cast<const short8v*>(krow + 8 * g);
      kf[kt][1] = (g < 2) ? *reinterpret_cast<const short8v*>(krow + 32 + 8 * g)
                          : zfrag;
    }
    short8v vf[3][2];
    #pragma unroll
    for (int dt = 0; dt < 3; ++dt)
      #pragma unroll
      for (int c = 0; c < 2; ++c)
        vf[dt][c] = *reinterpret_cast<const short8v*>(
            vbase + (size_t)(16 * dt + ql) * 1024 + ki * 64 + 32 * c + 8 * g);

    #pragma unroll
    for (int qt = 0; qt < 4; ++qt) {
      const int kts = (qt == 0) ? 0 : qt - 1;
      const int kte = (qt == 3) ? 3 : qt + 1;
      floatx4 s[4];
      #pragma unroll
      for (int kt = 0; kt < 4; ++kt) {
        if (kt < kts || kt > kte) continue;
        s[kt] = __builtin_amdgcn_mfma_f32_16x16x32_bf16(
            kf[kt][0], qf[qt][0], (floatx4){0.f, 0.f, 0.f, 0.f}, 0, 0, 0);
        s[kt] = __builtin_amdgcn_mfma_f32_16x16x32_bf16(
            kf[kt][1], qf[qt][1], s[kt], 0, 0, 0);
      }
      const int qcol = qt * 16 + ql;
      float pmax = -INFINITY;
      #pragma unroll
      for (int kt = 0; kt < 4; ++kt) {
        if (kt < kts || kt > kte) continue;
        #pragma unroll
        for (int r = 0; r < 4; ++r) {
          const int delta = kt * 16 + 4 * g + r - qcol;
          const bool ok = (delta <= 5) && (delta >= -5);
          s[kt][r] = ok ? s[kt][r] : -INFINITY;
          pmax = fmaxf(pmax, s[kt][r]);
        }
      }
      // defer-max (first ki: m=-inf -> always rescales/initializes)
      if (!__all(pmax - mreg[qt] <= 8.0f)) {
        float mt = fmaxf(pmax, __shfl_xor(pmax, 16, 64));
        mt = fmaxf(mt, __shfl_xor(mt, 32, 64));
        const float mnew = fmaxf(mreg[qt], mt);
        const float corr = __expf(mreg[qt] - mnew);
        lreg[qt] *= corr;
        #pragma unroll
        for (int dt = 0; dt < 3; ++dt) {
          ot[dt][qt][0] *= corr; ot[dt][qt][1] *= corr;
          ot[dt][qt][2] *= corr; ot[dt][qt][3] *= corr;
        }
        mreg[qt] = mnew;
      }
      float ps = 0.f;
      #pragma unroll
      for (int kt = 0; kt < 4; ++kt) {
        if (kt < kts || kt > kte) continue;
        #pragma unroll
        for (int r = 0; r < 4; ++r) {
          const float p = __expf(s[kt][r] - mreg[qt]);
          s[kt][r] = p;
          ps += p;
        }
      }
      ps += __shfl_xor(ps, 16, 64);
      ps += __shfl_xor(ps, 32, 64);
      lreg[qt] += ps;
      #pragma unroll
      for (int kt = 0; kt < 4; ++kt) {
        if (kt < kts || kt > kte) continue;
        uint2 pk;
        pk.x = (unsigned int)f2bu(s[kt][0]) | ((unsigned int)f2bu(s[kt][1]) << 16);
        pk.y = (unsigned int)f2bu(s[kt][2]) | ((unsigned int)f2bu(s[kt][3]) << 16);
        *reinterpret_cast<uint2*>(&plds[(qt * 16 + ql) * 72 + kt * 16 + 4 * g]) = pk;
      }
    }

    // PV band-skip: qt=0 band is k<32 (skip c=1); qt=3 band is k>=32 (skip c=0)
    __builtin_amdgcn_s_setprio(1);
    #pragma unroll
    for (int qt = 0; qt < 4; ++qt) {
      #pragma unroll
      for (int c = 0; c < 2; ++c) {
        if ((qt == 0 && c == 1) || (qt == 3 && c == 0)) continue;
        const short8v pf = *reinterpret_cast<const short8v*>(
            &plds[(qt * 16 + ql) * 72 + 32 * c + 8 * g]);
        #pragma unroll
        for (int dt = 0; dt < 3; ++dt)
          ot[dt][qt] = __builtin_amdgcn_mfma_f32_16x16x32_bf16(
              vf[dt][c], pf, ot[dt][qt], 0, 0, 0);
      }
    }
    __builtin_amdgcn_s_setprio(0);
  }

  // epilogue: normalize, store O^T -> attn_out[(b, i*64+q)][h*48 + d]
  const int b = bh >> 3, h = bh & 7;
  #pragma unroll
  for (int qt = 0; qt < 4; ++qt) {
    const float inv = 1.0f / lreg[qt];
    unsigned short* orow =
        attn_out + (size_t)(b * 1024 + i * 64 + qt * 16 + ql) * 384 + h * 48;
    #pragma unroll
    for (int dt = 0; dt < 3; ++dt) {
      const int d0 = 16 * dt + 4 * g;
      unsigned int w0 = (unsigned int)f2bu(ot[dt][qt][0] * inv) |
                        ((unsigned int)f2bu(ot[dt][qt][1] * inv) << 16);
      unsigned int w1 = (unsigned int)f2bu(ot[dt][qt][2] * inv) |
                        ((unsigned int)f2bu(ot[dt][qt][3] * inv) << 16);
      *reinterpret_cast<unsigned int*>(orow + d0)     = w0;
      *reinterpret_cast<unsigned int*>(orow + d0 + 2) = w1;
    }
  }
}

extern "C" void kernel_launch(void* const* d_in, const int* in_sizes, int n_in,
                              void* d_out, int out_size, void* d_ws, size_t ws_size,
                              hipStream_t stream) {
  const float* x      = (const float*)d_in[0];
  const float* w_qkv  = (const float*)d_in[1];
  const float* w_proj = (const float*)d_in[2];
  const float* b_proj = (const float*)d_in[3];
  // d_in[4] (mask) unused: window is analytic (|di|<=3, |dj|<=5)

  const size_t T = 25165824;  // 32768*384*2 bytes
  char* ws = (char*)d_ws;
  unsigned short* xb    = (unsigned short*)ws;            // aliased with attn_out
  unsigned short* qws   = (unsigned short*)(ws + T);
  unsigned short* kws   = (unsigned short*)(ws + 2 * T);
  unsigned short* vtws  = (unsigned short*)(ws + 3 * T);  // [bh][48][1024]
  unsigned short* wqkvT = (unsigned short*)(ws + 4 * T);
  unsigned short* wpT   = (unsigned short*)(ws + 4 * T + 884736);
  unsigned short* attn_out = xb;  // xb dead after K1
  float* out = (float*)d_out;

  // K0: conversions
  cvt_f32_bf16<<<12288, 256, 0, stream>>>((const float4*)x, (ushort4v*)xb, 3145728);
  transpose_cvt<<<dim3(36, 12), dim3(32, 8), 0, stream>>>(w_qkv, wqkvT, 384, 1152);
  transpose_cvt<<<dim3(12, 12), dim3(32, 8), 0, stream>>>(w_proj, wpT, 384, 384);

  // K1: qkv GEMM (M=32768, K=384, N=1152) -> q/k [bh][s][48], v^T [bh][48][s]
  gemm_mfma<0><<<dim3(9, 256), 256, 0, stream>>>(xb, wqkvT, nullptr, nullptr,
                                                 qws, kws, vtws);
  // K2: MFMA local attention -> attn_out bf16 [B*S, 384]
  attn_mfma<<<dim3(1024), 256, 0, stream>>>(qws, kws, vtws, attn_out);
  // K3: out = attn_out @ w_proj + bias (N=384), f32 out
  gemm_mfma<1><<<dim3(3, 256), 256, 0, stream>>>(attn_out, wpT, b_proj, out,
                                                 nullptr, nullptr, nullptr);
}

// Round 16
// 131.719 us; speedup vs baseline: 1.0836x; 1.0773x over previous
//
#include <hip/hip_runtime.h>
#include <hip/hip_bf16.h>

// Local-window attention, B=32 S=1024(16x64) H=8 D=384/8=48, window 7x11.
// R16: revert R14/R15's q/k LDS epilogue (regression: +7us vs R13's scatter).
//      GEMM now 8 waves x 512 threads per 128x128 tile (wave = 32m x 64n):
//      same LDS/swizzle/barriers as R13's BK=64 4-buffer loop, but 16 waves/CU
//      resident (was 8) on a latency-bound loop. Staging = 1 gload_lds per
//      thread per tile; vmcnt 8->4. q/k epilogue = R13 scatter; V = LDS
//      transpose (512-thread readback). attn = R13 + PV band-skip.

typedef __attribute__((ext_vector_type(8))) unsigned short ushort8;
typedef __attribute__((ext_vector_type(4))) unsigned short ushort4v;
typedef __attribute__((ext_vector_type(8))) short short8v;
typedef __attribute__((ext_vector_type(4))) float floatx4;

__device__ __forceinline__ float bf2f(unsigned short u) {
  union { unsigned int i; float f; } x;
  x.i = ((unsigned int)u) << 16;
  return x.f;
}

__device__ __forceinline__ unsigned short f2bu(float f) {
  union { float f; unsigned int i; } x;
  x.f = f;
  unsigned int lsb = (x.i >> 16) & 1u;
  x.i += 0x7FFFu + lsb;  // RNE
  return (unsigned short)(x.i >> 16);
}

__device__ __forceinline__ void gload_lds16(const void* g, void* l) {
  __builtin_amdgcn_global_load_lds(
      (const __attribute__((address_space(1))) unsigned int*)g,
      (__attribute__((address_space(3))) unsigned int*)l, 16, 0, 0);
}

// ---------------- K0a: f32 -> bf16 ----------------
__global__ __launch_bounds__(256) void cvt_f32_bf16(
    const float4* __restrict__ in, ushort4v* __restrict__ out, int n4) {
  const int i = blockIdx.x * 256 + threadIdx.x;
  if (i < n4) {
    const float4 v = in[i];
    ushort4v o;
    o[0] = f2bu(v.x); o[1] = f2bu(v.y); o[2] = f2bu(v.z); o[3] = f2bu(v.w);
    out[i] = o;
  }
}

// ---------------- K0b/c: transpose f32 [R][C] -> bf16 [C][R] ----------------
__global__ __launch_bounds__(256) void transpose_cvt(
    const float* __restrict__ in, unsigned short* __restrict__ out, int R, int C) {
  __shared__ float t[32][33];
  const int c0 = blockIdx.x * 32, r0 = blockIdx.y * 32;
  const int tx = threadIdx.x, ty = threadIdx.y;
  #pragma unroll
  for (int rr = ty; rr < 32; rr += 8) t[rr][tx] = in[(size_t)(r0 + rr) * C + c0 + tx];
  __syncthreads();
  #pragma unroll
  for (int rr = ty; rr < 32; rr += 8)
    out[(size_t)(c0 + rr) * R + r0 + tx] = f2bu(t[tx][rr]);
}

// ---------------- MFMA GEMM: 8-wave 512-thread, BK=64 4-buffer loop ----------
// Tile 128x128. Wave w: wm=w&3 (32-row strip), wn=w>>2 (64-col strip);
// acc[2][4]. LDS: A bufs at byte 0 (4 x 8KB), B bufs at 32768 (4 x 8KB).
// Thread t stages row t>>2, 16B slot (t&3)^((row&3)&3) swizzled — layout
// byte-identical to R13's (row*64 + swizzled slot). 1 gload_lds/thread/tile.
template <int MODE>
__global__ __launch_bounds__(512) void gemm_mfma(
    const unsigned short* __restrict__ A,   // [M][384] bf16
    const unsigned short* __restrict__ Bt,  // [N][384] bf16 (= B^T)
    const float* __restrict__ bias, float* __restrict__ outf,
    unsigned short* __restrict__ qws, unsigned short* __restrict__ kws,
    unsigned short* __restrict__ vtws)
{
  __shared__ unsigned short smem[32768];  // 64KB
  const int tid = threadIdx.x;
  const int lane = tid & 63, w = tid >> 6;
  const int wm = w & 3, wn = w >> 2;

  // chunked XCD swizzle
  const int nbx = gridDim.x;
  const int nwg = nbx * gridDim.y;
  const int bid = blockIdx.y * nbx + blockIdx.x;
  const int swz = (bid & 7) * (nwg >> 3) + (bid >> 3);
  const int n0 = (swz % nbx) * 128;
  const int m0 = (swz / nbx) * 128;

  floatx4 acc[2][4];
  #pragma unroll
  for (int mi = 0; mi < 2; ++mi)
    #pragma unroll
    for (int ni = 0; ni < 4; ++ni)
      acc[mi][ni] = (floatx4){0.f, 0.f, 0.f, 0.f};

  const int srow = tid >> 2;            // 0..127
  const int kslot16 = (tid & 3) * 16;

  auto ASB = [&](int buf) -> char* { return (char*)smem + buf * 8192; };
  auto BSB = [&](int buf) -> char* { return (char*)smem + 32768 + buf * 8192; };

  auto STAGE = [&](int buf, int k0) {
    const int kb = kslot16 ^ ((srow & 3) << 4);
    gload_lds16((const char*)A + (size_t)(m0 + srow) * 768 + k0 * 2 + kb,
                ASB(buf) + w * 1024);
    gload_lds16((const char*)Bt + (size_t)(n0 + srow) * 768 + k0 * 2 + kb,
                BSB(buf) + w * 1024);
  };

  auto COMPUTE = [&](int buf) {
    short8v a[2], b[4];
    const int kgb = (lane >> 4) * 16;
    #pragma unroll
    for (int mi = 0; mi < 2; ++mi) {
      const int r = wm * 32 + mi * 16 + (lane & 15);
      a[mi] = *reinterpret_cast<const short8v*>(
          ASB(buf) + r * 64 + (kgb ^ ((r & 3) << 4)));
    }
    #pragma unroll
    for (int ni = 0; ni < 4; ++ni) {
      const int r = wn * 64 + ni * 16 + (lane & 15);
      b[ni] = *reinterpret_cast<const short8v*>(
          BSB(buf) + r * 64 + (kgb ^ ((r & 3) << 4)));
    }
    #pragma unroll
    for (int mi = 0; mi < 2; ++mi)
      #pragma unroll
      for (int ni = 0; ni < 4; ++ni)
        acc[mi][ni] = __builtin_amdgcn_mfma_f32_16x16x32_bf16(
            a[mi], b[ni], acc[mi][ni], 0, 0, 0);
  };

  STAGE(0, 0);
  STAGE(1, 32);

  #pragma unroll
  for (int s = 0; s < 6; ++s) {
    const int rb = (s & 1) * 2;  // read bufs rb, rb+1 (tiles 2s, 2s+1)
    const int sb = rb ^ 2;       // stage bufs (tiles 2s+2, 2s+3)
    if (s < 5) {
      STAGE(sb, (2 * s + 2) * 32);
      STAGE(sb + 1, (2 * s + 3) * 32);
      asm volatile("s_waitcnt vmcnt(4)" ::: "memory");  // read-pair loads done
    } else {
      asm volatile("s_waitcnt vmcnt(0)" ::: "memory");
    }
    __builtin_amdgcn_s_barrier();
    __builtin_amdgcn_s_setprio(1);
    COMPUTE(rb);
    COMPUTE(rb + 1);
    __builtin_amdgcn_s_setprio(0);
    asm volatile("s_waitcnt lgkmcnt(0)" ::: "memory");
    __builtin_amdgcn_s_barrier();
  }

  const int col_l = lane & 15;
  const int row_l = (lane >> 4) * 4;

  if (MODE == 0) {
    const float QSCALE = 0.14433756729740643f;  // 1/sqrt(48)
    const int which = n0 / 384;  // uniform per block (384 | 128*{0,3,6})
    if (which < 2) {
      // q/k: R13 direct scatter (4x32B row segments per store instr — proven
      // faster than the LDS round-trip at 2 blocks/CU).
      unsigned short* dstb = (which == 0) ? qws : kws;
      const float scale = (which == 0) ? QSCALE : 1.f;
      #pragma unroll
      for (int ni = 0; ni < 4; ++ni) {
        const int cg = n0 + wn * 64 + ni * 16 + col_l;
        const int rem = cg - which * 384;
        const int h = rem / 48;
        const int d = rem - h * 48;
        #pragma unroll
        for (int mi = 0; mi < 2; ++mi) {
          #pragma unroll
          for (int reg = 0; reg < 4; ++reg) {
            const int r = m0 + wm * 32 + mi * 16 + row_l + reg;
            const int bb = r >> 10, s = r & 1023;
            dstb[(((size_t)(bb * 8 + h)) * 1024 + s) * 48 + d] =
                f2bu(acc[mi][ni][reg] * scale);
          }
        }
      }
    } else {
      // V: transpose C-tile through LDS, coalesced vt writes (R11-verified,
      // readback re-indexed for 512 threads: 4 x 16B per thread).
      unsigned short* T = smem;  // 128*136 = 17408 shorts, aliases staging
      #pragma unroll
      for (int ni = 0; ni < 4; ++ni) {
        const int col = wn * 64 + ni * 16 + col_l;
        #pragma unroll
        for (int mi = 0; mi < 2; ++mi) {
          const int rowb = wm * 32 + mi * 16 + row_l;
          #pragma unroll
          for (int reg = 0; reg < 4; ++reg)
            T[col * 136 + rowb + reg] = f2bu(acc[mi][ni][reg]);
        }
      }
      __syncthreads();
      const int col = tid >> 2, q = tid & 3;
      const int cg = n0 + col;
      const int rem = cg - 768;
      const int h = rem / 48, d = rem - h * 48;
      const int bb = m0 >> 10;
      const int s0 = (m0 & 1023) + q * 32;
      unsigned short* dst =
          vtws + (((size_t)(bb * 8 + h)) * 48 + d) * 1024 + s0;
      const unsigned short* src = T + col * 136 + q * 32;
      #pragma unroll
      for (int j = 0; j < 4; ++j)
        *reinterpret_cast<ushort8*>(dst + j * 8) =
            *reinterpret_cast<const ushort8*>(src + j * 8);
    }
  } else {
    #pragma unroll
    for (int ni = 0; ni < 4; ++ni) {
      const int cg = n0 + wn * 64 + ni * 16 + col_l;
      const float bv = bias[cg];
      #pragma unroll
      for (int mi = 0; mi < 2; ++mi) {
        #pragma unroll
        for (int reg = 0; reg < 4; ++reg) {
          const int r = m0 + wm * 32 + mi * 16 + row_l + reg;
          outf[(size_t)r * 384 + cg] = acc[mi][ni][reg] + bv;
        }
      }
    }
  }
}

// ---------------- K2: MFMA local attention (R13 + PV band-skip) ----------
__global__ __launch_bounds__(256) void attn_mfma(
    const unsigned short* __restrict__ qws,  // [bh][1024][48]
    const unsigned short* __restrict__ kws,  // [bh][1024][48]
    const unsigned short* __restrict__ vt,   // [bh][48][1024]
    unsigned short* __restrict__ attn_out)   // [b*1024][384] bf16
{
  __shared__ unsigned short plds_all[4 * 64 * 72];

  const int tid = threadIdx.x;
  const int w = tid >> 6;
  const int lane = tid & 63;
  const int blk = blockIdx.x;
  const int sw = ((blk & 7) << 7) | (blk >> 3);  // 1024 % 8 == 0
  const int task = sw * 4 + w;
  const int i  = task & 15;
  const int bh = task >> 4;
  const int ql = lane & 15;
  const int g  = lane >> 4;

  unsigned short* plds = plds_all + w * 4608;  // 64*72 per wave

  // zero plds once: band-external tiles stay 0 forever -> PV adds exact zeros
  {
    const uint4 zz = make_uint4(0, 0, 0, 0);
    #pragma unroll
    for (int z = 0; z < 9; ++z)
      reinterpret_cast<uint4*>(plds)[lane + z * 64] = zz;
  }

  const unsigned short* qbase = qws + (size_t)bh * 1024 * 48;
  const unsigned short* kbase = kws + (size_t)bh * 1024 * 48;
  const unsigned short* vbase = vt  + (size_t)bh * 48 * 1024;

  const short8v zfrag = (short8v){0, 0, 0, 0, 0, 0, 0, 0};

  short8v qf[4][2];
  #pragma unroll
  for (int qt = 0; qt < 4; ++qt) {
    const unsigned short* qrow = qbase + (size_t)(i * 64 + qt * 16 + ql) * 48;
    qf[qt][0] = *reinterpret_cast<const short8v*>(qrow + 8 * g);
    qf[qt][1] = (g < 2) ? *reinterpret_cast<const short8v*>(qrow + 32 + 8 * g)
                        : zfrag;
  }

  floatx4 ot[3][4];
  #pragma unroll
  for (int dt = 0; dt < 3; ++dt)
    #pragma unroll
    for (int qt = 0; qt < 4; ++qt)
      ot[dt][qt] = (floatx4){0.f, 0.f, 0.f, 0.f};
  float mreg[4] = {-INFINITY, -INFINITY, -INFINITY, -INFINITY};
  float lreg[4] = {0.f, 0.f, 0.f, 0.f};

  const int ki0 = (i - 3 < 0) ? 0 : i - 3;
  const int ki1 = (i + 3 > 15) ? 15 : i + 3;

  for (int ki = ki0; ki <= ki1; ++ki) {
    short8v kf[4][2];
    #pragma unroll
    for (int kt = 0; kt < 4; ++kt) {
      const unsigned short* krow = kbase + (size_t)(ki * 64 + kt * 16 + ql) * 48;
      kf[kt][0] = *reinterpret_cast<const short8v*>(krow + 8 * g);
      kf[kt][1] = (g < 2) ? *reinterpret_cast<const short8v*>(krow + 32 + 8 * g)
                          : zfrag;
    }
    short8v vf[3][2];
    #pragma unroll
    for (int dt = 0; dt < 3; ++dt)
      #pragma unroll
      for (int c = 0; c < 2; ++c)
        vf[dt][c] = *reinterpret_cast<const short8v*>(
            vbase + (size_t)(16 * dt + ql) * 1024 + ki * 64 + 32 * c + 8 * g);

    #pragma unroll
    for (int qt = 0; qt < 4; ++qt) {
      const int kts = (qt == 0) ? 0 : qt - 1;
      const int kte = (qt == 3) ? 3 : qt + 1;
      floatx4 s[4];
      #pragma unroll
      for (int kt = 0; kt < 4; ++kt) {
        if (kt < kts || kt > kte) continue;
        s[kt] = __builtin_amdgcn_mfma_f32_16x16x32_bf16(
            kf[kt][0], qf[qt][0], (floatx4){0.f, 0.f, 0.f, 0.f}, 0, 0, 0);
        s[kt] = __builtin_amdgcn_mfma_f32_16x16x32_bf16(
            kf[kt][1], qf[qt][1], s[kt], 0, 0, 0);
      }
      const int qcol = qt * 16 + ql;
      float pmax = -INFINITY;
      #pragma unroll
      for (int kt = 0; kt < 4; ++kt) {
        if (kt < kts || kt > kte) continue;
        #pragma unroll
        for (int r = 0; r < 4; ++r) {
          const int delta = kt * 16 + 4 * g + r - qcol;
          const bool ok = (delta <= 5) && (delta >= -5);
          s[kt][r] = ok ? s[kt][r] : -INFINITY;
          pmax = fmaxf(pmax, s[kt][r]);
        }
      }
      // defer-max (first ki: m=-inf -> always rescales/initializes)
      if (!__all(pmax - mreg[qt] <= 8.0f)) {
        float mt = fmaxf(pmax, __shfl_xor(pmax, 16, 64));
        mt = fmaxf(mt, __shfl_xor(mt, 32, 64));
        const float mnew = fmaxf(mreg[qt], mt);
        const float corr = __expf(mreg[qt] - mnew);
        lreg[qt] *= corr;
        #pragma unroll
        for (int dt = 0; dt < 3; ++dt) {
          ot[dt][qt][0] *= corr; ot[dt][qt][1] *= corr;
          ot[dt][qt][2] *= corr; ot[dt][qt][3] *= corr;
        }
        mreg[qt] = mnew;
      }
      float ps = 0.f;
      #pragma unroll
      for (int kt = 0; kt < 4; ++kt) {
        if (kt < kts || kt > kte) continue;
        #pragma unroll
        for (int r = 0; r < 4; ++r) {
          const float p = __expf(s[kt][r] - mreg[qt]);
          s[kt][r] = p;
          ps += p;
        }
      }
      ps += __shfl_xor(ps, 16, 64);
      ps += __shfl_xor(ps, 32, 64);
      lreg[qt] += ps;
      #pragma unroll
      for (int kt = 0; kt < 4; ++kt) {
        if (kt < kts || kt > kte) continue;
        uint2 pk;
        pk.x = (unsigned int)f2bu(s[kt][0]) | ((unsigned int)f2bu(s[kt][1]) << 16);
        pk.y = (unsigned int)f2bu(s[kt][2]) | ((unsigned int)f2bu(s[kt][3]) << 16);
        *reinterpret_cast<uint2*>(&plds[(qt * 16 + ql) * 72 + kt * 16 + 4 * g]) = pk;
      }
    }

    // PV band-skip: qt=0 band is k<32 (skip c=1); qt=3 band is k>=32 (skip c=0)
    __builtin_amdgcn_s_setprio(1);
    #pragma unroll
    for (int qt = 0; qt < 4; ++qt) {
      #pragma unroll
      for (int c = 0; c < 2; ++c) {
        if ((qt == 0 && c == 1) || (qt == 3 && c == 0)) continue;
        const short8v pf = *reinterpret_cast<const short8v*>(
            &plds[(qt * 16 + ql) * 72 + 32 * c + 8 * g]);
        #pragma unroll
        for (int dt = 0; dt < 3; ++dt)
          ot[dt][qt] = __builtin_amdgcn_mfma_f32_16x16x32_bf16(
              vf[dt][c], pf, ot[dt][qt], 0, 0, 0);
      }
    }
    __builtin_amdgcn_s_setprio(0);
  }

  // epilogue: normalize, store O^T -> attn_out[(b, i*64+q)][h*48 + d]
  const int b = bh >> 3, h = bh & 7;
  #pragma unroll
  for (int qt = 0; qt < 4; ++qt) {
    const float inv = 1.0f / lreg[qt];
    unsigned short* orow =
        attn_out + (size_t)(b * 1024 + i * 64 + qt * 16 + ql) * 384 + h * 48;
    #pragma unroll
    for (int dt = 0; dt < 3; ++dt) {
      const int d0 = 16 * dt + 4 * g;
      unsigned int w0 = (unsigned int)f2bu(ot[dt][qt][0] * inv) |
                        ((unsigned int)f2bu(ot[dt][qt][1] * inv) << 16);
      unsigned int w1 = (unsigned int)f2bu(ot[dt][qt][2] * inv) |
                        ((unsigned int)f2bu(ot[dt][qt][3] * inv) << 16);
      *reinterpret_cast<unsigned int*>(orow + d0)     = w0;
      *reinterpret_cast<unsigned int*>(orow + d0 + 2) = w1;
    }
  }
}

extern "C" void kernel_launch(void* const* d_in, const int* in_sizes, int n_in,
                              void* d_out, int out_size, void* d_ws, size_t ws_size,
                              hipStream_t stream) {
  const float* x      = (const float*)d_in[0];
  const float* w_qkv  = (const float*)d_in[1];
  const float* w_proj = (const float*)d_in[2];
  const float* b_proj = (const float*)d_in[3];
  // d_in[4] (mask) unused: window is analytic (|di|<=3, |dj|<=5)

  const size_t T = 25165824;  // 32768*384*2 bytes
  char* ws = (char*)d_ws;
  unsigned short* xb    = (unsigned short*)ws;            // aliased with attn_out
  unsigned short* qws   = (unsigned short*)(ws + T);
  unsigned short* kws   = (unsigned short*)(ws + 2 * T);
  unsigned short* vtws  = (unsigned short*)(ws + 3 * T);  // [bh][48][1024]
  unsigned short* wqkvT = (unsigned short*)(ws + 4 * T);
  unsigned short* wpT   = (unsigned short*)(ws + 4 * T + 884736);
  unsigned short* attn_out = xb;  // xb dead after K1
  float* out = (float*)d_out;

  // K0: conversions
  cvt_f32_bf16<<<12288, 256, 0, stream>>>((const float4*)x, (ushort4v*)xb, 3145728);
  transpose_cvt<<<dim3(36, 12), dim3(32, 8), 0, stream>>>(w_qkv, wqkvT, 384, 1152);
  transpose_cvt<<<dim3(12, 12), dim3(32, 8), 0, stream>>>(w_proj, wpT, 384, 384);

  // K1: qkv GEMM (M=32768, K=384, N=1152) -> q/k [bh][s][48], v^T [bh][48][s]
  gemm_mfma<0><<<dim3(9, 256), 512, 0, stream>>>(xb, wqkvT, nullptr, nullptr,
                                                 qws, kws, vtws);
  // K2: MFMA local attention -> attn_out bf16 [B*S, 384]
  attn_mfma<<<dim3(1024), 256, 0, stream>>>(qws, kws, vtws, attn_out);
  // K3: out = attn_out @ w_proj + bias (N=384), f32 out
  gemm_mfma<1><<<dim3(3, 256), 512, 0, stream>>>(attn_out, wpT, b_proj, out,
                                                 nullptr, nullptr, nullptr);
}